// Round 7
// baseline (239.016 us; speedup 1.0000x reference)
//
#include <hip/hip_runtime.h>

#define N_NODES 20000
#define N_REL 200
#define N_EDGES 200000
#define DIM 128
#define T_STEPS 8
#define N_TILES (N_NODES / 16)              // 1250
#define CAP 512                             // bucket slots per 16-node tile

typedef short short8 __attribute__((ext_vector_type(8)));
typedef float f32x4 __attribute__((ext_vector_type(4)));

static __device__ __forceinline__ unsigned short f2bf(float f) {
  union { float f; unsigned u; } v; v.f = f;
  unsigned r = v.u + 0x7fffu + ((v.u >> 16) & 1u);   // RNE
  return (unsigned short)(r >> 16);
}
// packed f32x2 -> bf16x2 (RNE), 1 instruction
static __device__ __forceinline__ unsigned cvt_pk_bf16(float lo, float hi) {
  unsigned r;
  asm("v_cvt_pk_bf16_f32 %0, %1, %2" : "=v"(r) : "v"(lo), "v"(hi));
  return r;
}
static __device__ __forceinline__ float fast_tanh(float x) {
  float e = __expf(2.f * x);           // inf-safe: x>>0 -> 1, x<<0 -> -1
  return 1.f - 2.f / (e + 1.f);
}
static __device__ __forceinline__ float fast_sig(float x) {
  return 1.f / (1.f + __expf(-x));
}

// ---------------------------------------------------------------------------
// Repack the five 128x128 fp32 weight matrices (row-major W[k][n]) into bf16
// MFMA B-fragment order: pack[m][((nt*4+ks)*64+lane)*8+j] = bf16(W[k][n]),
// n = nt*16 + (lane&15), k = ks*32 + (lane>>4)*8 + j.
// Slots: 0=Wenc 1=Wz 2=Uz 3=Wh 4=Uh.
// Also zeroes the 1250 bucket cursors (replaces the hipMemsetAsync dispatch).
// ---------------------------------------------------------------------------
__global__ void repack5(const float* __restrict__ w0,
                        const float* __restrict__ w1,
                        const float* __restrict__ w2,
                        const float* __restrict__ w3,
                        const float* __restrict__ w4,
                        unsigned short* __restrict__ pack,
                        int* __restrict__ cursor) {
  int i = blockIdx.x * blockDim.x + threadIdx.x;
  if (i < N_TILES) cursor[i] = 0;
  if (i >= 5 * 16384) return;
  int m = i >> 14, r = i & 16383;
  int j = r & 7, lane = (r >> 3) & 63, ks = (r >> 9) & 3, nt = (r >> 11) & 7;
  int n = nt * 16 + (lane & 15);
  int k = ks * 32 + (lane >> 4) * 8 + j;
  const float* w = (m == 0) ? w0 : (m == 1) ? w1 : (m == 2) ? w2
                 : (m == 3) ? w3 : w4;
  pack[i] = f2bf(w[k * DIM + n]);
}

// ---------------------------------------------------------------------------
// Bucket-scatter: bin edges by dst-tile (16 nodes/tile), NO prefix scan.
// meta = src | rel<<15 | t<<23 | node_local<<26  (15+8+3+4 = 30 bits).
// CAP=512 vs mean 160 (sigma 12.6): overflow probability ~0; pos<CAP guard
// makes it non-UB regardless (dropped edge, never triggered for this data).
// Replaces hist_k + scan1_k + scan2_k + fill_k + the counts memset.
// ---------------------------------------------------------------------------
__global__ void binfill_k(const int* __restrict__ src, const int* __restrict__ dst,
                          const int* __restrict__ etype, const int* __restrict__ etime,
                          const float* __restrict__ ew,
                          int* __restrict__ cursor, uint2* __restrict__ bkt) {
  int i = blockIdx.x * blockDim.x + threadIdx.x;
  if (i >= N_EDGES) return;
  int d = dst[i];
  int tile = d >> 4;
  int pos = atomicAdd(&cursor[tile], 1);
  if (pos < CAP) {
    uint2 e;
    e.x = (unsigned)src[i] | ((unsigned)etype[i] << 15)
        | ((unsigned)etime[i] << 23) | ((unsigned)(d & 15) << 26);
    e.y = __float_as_uint(ew[i]);
    bkt[(size_t)tile * CAP + pos] = e;
  }
}

// ---------------------------------------------------------------------------
// Fully-fused GATHER + encoder + GRU recurrence. One block per 16-node tile,
// 8 waves.
// Phase A (gather): all 8 waves scan the tile's ~160 bucketed edges (meta is
//   one uint2/edge, same line for all waves -> L1 broadcast). Ownership test
//   (node_local>>1)==wave is wave-uniform -> non-owned edges skip their
//   nemb/remb row loads entirely. Owned edges accumulate into 32 registers
//   (2 nodes x 8 t x 2 dims, t-predicated adds -- R0's proven pattern).
//   Rows written packed-bf16 to aggL (u32/lane, contiguous -> conflict-free).
//   Summation order within (node,t) = bucket order (atomic arrival): differs
//   from the reference's edge order only in f32 rounding, ~1e-5 vs the
//   ~8e-3 bf16 quantization floor.
// ONE barrier, then:
// Phase B (encoder, hoisted): wave nt owns column tile nt; A-frags for all
//   8 t read from aggL (stride 136 shorts: 2-way bank alias = free, m136);
//   32 MFMAs with wenc -> hpk[t] packed bf16 (16 VGPRs).
// Phase C (recurrence, best-measured R1 structure): per step t: H[t],S ->
//   double-buffered LDS (stride 136), ONE barrier, re-read as A-frags
//   (full 128-K), 16 MFMAs, gated update.
// MFMA 16x16x32_bf16 layouts (HW-verified): A: m=lane&15,k=quad*8+j;
// B: n=lane&15,k=quad*8+j;  C/D: col=lane&15, row=quad*4+reg.
// Double-buffer WAR safety: writes of buffer X at step t+2 are ordered after
// barrier(t+1), which is after all reads of X at step t. aggL is written
// only in phase A (barrier-protected) and read-only afterwards.
// ---------------------------------------------------------------------------
__launch_bounds__(512, 4)
__global__ void fused_recur(const int* __restrict__ cursor,
                            const uint2* __restrict__ bkt,
                            const float* __restrict__ nemb,
                            const float* __restrict__ remb,
                            const unsigned short* __restrict__ pack,
                            const float* __restrict__ bz,
                            const float* __restrict__ bh,
                            float* __restrict__ out) {
  __shared__ unsigned short aggL[T_STEPS * 16 * 136];   // 34816 B
  __shared__ unsigned short Hb[2][16 * 136];            //  8704 B
  __shared__ unsigned short Sb[2][16 * 136];            //  8704 B
  int lane = threadIdx.x & 63;
  int nt = threadIdx.x >> 6;        // wave id: owns nodes {2nt,2nt+1} / col tile nt
  int q = lane >> 4, l15 = lane & 15;
  int tile = blockIdx.x;
  int row0 = tile * 16;
  int c = nt * 16 + l15;

  // ---- Phase A: scan tile bucket, accumulate this wave's 2 nodes ----
  {
    int cnt = cursor[tile];
    if (cnt > CAP) cnt = CAP;
    const uint2* bp = bkt + (size_t)tile * CAP;
    float ax0[T_STEPS], ay0[T_STEPS], ax1[T_STEPS], ay1[T_STEPS];
#pragma unroll
    for (int tt = 0; tt < T_STEPS; tt++) {
      ax0[tt] = 0.f; ay0[tt] = 0.f; ax1[tt] = 0.f; ay1[tt] = 0.f;
    }
    for (int i = 0; i < cnt; i++) {
      uint2 e = bp[i];
      int nl = (int)(e.x >> 26);
      if ((nl >> 1) == nt) {                    // wave-uniform branch
        int s = e.x & 0x7fff, rt = (e.x >> 15) & 0xff, t = (e.x >> 23) & 7;
        float w = __uint_as_float(e.y);
        float2 sv = ((const float2*)(nemb + (size_t)s * DIM))[lane];
        float2 rv = ((const float2*)(remb + (size_t)rt * DIM))[lane];
        float m0 = sv.x * rv.x * w;
        float m1 = sv.y * rv.y * w;
        bool odd = nl & 1;
        float e00 = odd ? 0.f : m0, e01 = odd ? 0.f : m1;
        float e10 = odd ? m0 : 0.f, e11 = odd ? m1 : 0.f;
#pragma unroll
        for (int tt = 0; tt < T_STEPS; tt++) {
          bool h = (t == tt);
          ax0[tt] += h ? e00 : 0.f;
          ay0[tt] += h ? e01 : 0.f;
          ax1[tt] += h ? e10 : 0.f;
          ay1[tt] += h ? e11 : 0.f;
        }
      }
    }
#pragma unroll
    for (int tt = 0; tt < T_STEPS; tt++) {
      ((unsigned*)&aggL[(tt * 16 + nt * 2 + 0) * 136])[lane] = cvt_pk_bf16(ax0[tt], ay0[tt]);
      ((unsigned*)&aggL[(tt * 16 + nt * 2 + 1) * 136])[lane] = cvt_pk_bf16(ax1[tt], ay1[tt]);
    }
  }
  __syncthreads();

  // ---- Phase B: encoder for ALL steps: H[t](:, nt-cols) as packed bf16 ----
  unsigned hpk[T_STEPS][2];
  {
    short8 wenc[4];
#pragma unroll
    for (int ks = 0; ks < 4; ks++)
      wenc[ks] = *(const short8*)(pack + ((nt * 4 + ks) * 64 + lane) * 8);
#pragma unroll
    for (int t = 0; t < T_STEPS; t++) {
      f32x4 acch = (f32x4){0.f, 0.f, 0.f, 0.f};
#pragma unroll
      for (int ks = 0; ks < 4; ks++) {
        short8 aA = *(const short8*)&aggL[(t * 16 + l15) * 136 + ks * 32 + q * 8];
        acch = __builtin_amdgcn_mfma_f32_16x16x32_bf16(aA, wenc[ks], acch, 0, 0, 0);
      }
      hpk[t][0] = cvt_pk_bf16(fast_tanh(acch[0]), fast_tanh(acch[1]));
      hpk[t][1] = cvt_pk_bf16(fast_tanh(acch[2]), fast_tanh(acch[3]));
    }
  }

  // recurrence weight B-fragments for this wave's nt
  short8 wz[4], uz[4], wh[4], uh[4];
#pragma unroll
  for (int ks = 0; ks < 4; ks++) {
    int fo = ((nt * 4 + ks) * 64 + lane) * 8;
    wz[ks] = *(const short8*)(pack + 16384 * 1 + fo);
    uz[ks] = *(const short8*)(pack + 16384 * 2 + fo);
    wh[ks] = *(const short8*)(pack + 16384 * 3 + fo);
    uh[ks] = *(const short8*)(pack + 16384 * 4 + fo);
  }
  float bzv = bz[c];
  float bhv = bh[c];

  f32x4 stC = (f32x4){0.f, 0.f, 0.f, 0.f};

  // ---- Phase C: GRU recurrence (best-measured R1 structure) ----
#pragma unroll
  for (int t = 0; t < T_STEPS; t++) {
    unsigned short* hB = Hb[t & 1];
    unsigned short* sB = Sb[t & 1];
    unsigned s01 = cvt_pk_bf16(stC[0], stC[1]);
    unsigned s23 = cvt_pk_bf16(stC[2], stC[3]);
    hB[(q * 4 + 0) * 136 + c] = (unsigned short)hpk[t][0];
    hB[(q * 4 + 1) * 136 + c] = (unsigned short)(hpk[t][0] >> 16);
    hB[(q * 4 + 2) * 136 + c] = (unsigned short)hpk[t][1];
    hB[(q * 4 + 3) * 136 + c] = (unsigned short)(hpk[t][1] >> 16);
    sB[(q * 4 + 0) * 136 + c] = (unsigned short)s01;
    sB[(q * 4 + 1) * 136 + c] = (unsigned short)(s01 >> 16);
    sB[(q * 4 + 2) * 136 + c] = (unsigned short)s23;
    sB[(q * 4 + 3) * 136 + c] = (unsigned short)(s23 >> 16);
    __syncthreads();

    f32x4 accz = (f32x4){bzv, bzv, bzv, bzv};
    f32x4 accc = (f32x4){bhv, bhv, bhv, bhv};
#pragma unroll
    for (int ks = 0; ks < 4; ks++) {
      short8 hA = *(const short8*)&hB[l15 * 136 + ks * 32 + q * 8];
      short8 sA = *(const short8*)&sB[l15 * 136 + ks * 32 + q * 8];
      accz = __builtin_amdgcn_mfma_f32_16x16x32_bf16(hA, wz[ks], accz, 0, 0, 0);
      accz = __builtin_amdgcn_mfma_f32_16x16x32_bf16(sA, uz[ks], accz, 0, 0, 0);
      accc = __builtin_amdgcn_mfma_f32_16x16x32_bf16(hA, wh[ks], accc, 0, 0, 0);
      accc = __builtin_amdgcn_mfma_f32_16x16x32_bf16(sA, uh[ks], accc, 0, 0, 0);
    }
#pragma unroll
    for (int r = 0; r < 4; r++) {
      float z = fast_sig(accz[r]);
      float cc = fast_tanh(accc[r]);
      stC[r] = (1.f - z) * stC[r] + z * cc;
    }
  }

  // final state -> out (fp32, C-layout positions)
#pragma unroll
  for (int r = 0; r < 4; r++)
    out[(size_t)(row0 + q * 4 + r) * DIM + c] = stC[r];
}

extern "C" void kernel_launch(void* const* d_in, const int* in_sizes, int n_in,
                              void* d_out, int out_size, void* d_ws, size_t ws_size,
                              hipStream_t stream) {
  const int* eidx  = (const int*)d_in[0];
  const int* src   = eidx;
  const int* dst   = eidx + N_EDGES;
  const int* etype = (const int*)d_in[1];
  const int* etime = (const int*)d_in[2];
  const float* ew   = (const float*)d_in[3];
  const float* nemb = (const float*)d_in[4];
  const float* remb = (const float*)d_in[5];
  const float* Wenc = (const float*)d_in[6];
  const float* Wz   = (const float*)d_in[7];
  const float* Uz   = (const float*)d_in[8];
  const float* Wh   = (const float*)d_in[9];
  const float* Uh   = (const float*)d_in[10];
  const float* bz   = (const float*)d_in[11];
  const float* bh   = (const float*)d_in[12];
  // d_in[13] = num_times (constant 8 for this problem's fixed shapes)

  // ws layout: cursor | bkt | pack
  int* cursor = (int*)d_ws;                                        // N_TILES
  uint2* bkt  = (uint2*)(cursor + ((N_TILES + 1) & ~1));           // N_TILES*CAP (5.1 MB)
  unsigned short* pack = (unsigned short*)(bkt + (size_t)N_TILES * CAP); // 5*16384
  float* outp = (float*)d_out;

  repack5<<<(5 * 16384 + 255) / 256, 256, 0, stream>>>(Wenc, Wz, Uz, Wh, Uh,
                                                       pack, cursor);
  binfill_k<<<(N_EDGES + 255) / 256, 256, 0, stream>>>(src, dst, etype, etime,
                                                       ew, cursor, bkt);
  fused_recur<<<N_TILES, 512, 0, stream>>>(cursor, bkt, nemb, remb,
                                           pack, bz, bh, outp);
}

// Round 9
// 214.244 us; speedup vs baseline: 1.1156x; 1.1156x over previous
//
#include <hip/hip_runtime.h>

#define N_NODES 20000
#define N_REL 200
#define N_EDGES 200000
#define DIM 128
#define T_STEPS 8
#define N_TILES (N_NODES / 16)              // 1250
#define KEYS (N_NODES * T_STEPS)            // 160000 (dst,t) segments
#define SCAN_N (KEYS + 1)                   // 160001
#define SCAN_BLKS ((SCAN_N + 1023) / 1024)  // 157

typedef short short8 __attribute__((ext_vector_type(8)));
typedef float f32x4 __attribute__((ext_vector_type(4)));

static __device__ __forceinline__ unsigned short f2bf(float f) {
  union { float f; unsigned u; } v; v.f = f;
  unsigned r = v.u + 0x7fffu + ((v.u >> 16) & 1u);   // RNE
  return (unsigned short)(r >> 16);
}
// packed f32x2 -> bf16x2 (RNE), 1 instruction
static __device__ __forceinline__ unsigned cvt_pk_bf16(float lo, float hi) {
  unsigned r;
  asm("v_cvt_pk_bf16_f32 %0, %1, %2" : "=v"(r) : "v"(lo), "v"(hi));
  return r;
}
static __device__ __forceinline__ float fast_tanh(float x) {
  float e = __expf(2.f * x);           // inf-safe: x>>0 -> 1, x<<0 -> -1
  return 1.f - 2.f / (e + 1.f);
}
static __device__ __forceinline__ float fast_sig(float x) {
  return 1.f / (1.f + __expf(-x));
}

// ---------------------------------------------------------------------------
// Repack the five 128x128 fp32 weight matrices (row-major W[k][n]) into bf16
// MFMA B-fragment order: pack[m][((nt*4+ks)*64+lane)*8+j] = bf16(W[k][n]),
// n = nt*16 + (lane&15), k = ks*32 + (lane>>4)*8 + j.
// Slots: 0=Wenc 1=Wz 2=Uz 3=Wh 4=Uh.
// ---------------------------------------------------------------------------
__global__ void repack5(const float* __restrict__ w0,
                        const float* __restrict__ w1,
                        const float* __restrict__ w2,
                        const float* __restrict__ w3,
                        const float* __restrict__ w4,
                        unsigned short* __restrict__ pack) {
  int i = blockIdx.x * blockDim.x + threadIdx.x;
  if (i >= 5 * 16384) return;
  int m = i >> 14, r = i & 16383;
  int j = r & 7, lane = (r >> 3) & 63, ks = (r >> 9) & 3, nt = (r >> 11) & 7;
  int n = nt * 16 + (lane & 15);
  int k = ks * 32 + (lane >> 4) * 8 + j;
  const float* w = (m == 0) ? w0 : (m == 1) ? w1 : (m == 2) ? w2
                 : (m == 3) ? w3 : w4;
  pack[i] = f2bf(w[k * DIM + n]);
}

// ----------------- CSR build: bucket by key = dst*8 + t --------------------
__global__ void hist_k(const int* __restrict__ dst, const int* __restrict__ etime,
                       int* __restrict__ counts) {
  int i = blockIdx.x * blockDim.x + threadIdx.x;
  if (i >= N_EDGES) return;
  atomicAdd(&counts[dst[i] * T_STEPS + etime[i]], 1);
}

__global__ void scan1_k(const int* __restrict__ counts,
                        int* __restrict__ base, int* __restrict__ bsum) {
  __shared__ int ls[256];
  int tid = threadIdx.x;
  int i0 = blockIdx.x * 1024 + tid * 4;
  int v[4], ts = 0;
#pragma unroll
  for (int r = 0; r < 4; r++) {
    v[r] = (i0 + r < SCAN_N) ? counts[i0 + r] : 0;
    ts += v[r];
  }
  ls[tid] = ts; __syncthreads();
#pragma unroll
  for (int off = 1; off < 256; off <<= 1) {
    int x = (tid >= off) ? ls[tid - off] : 0;
    __syncthreads(); ls[tid] += x; __syncthreads();
  }
  int run = ls[tid] - ts;
  if (tid == 255) bsum[blockIdx.x] = ls[255];
#pragma unroll
  for (int r = 0; r < 4; r++) {
    if (i0 + r < SCAN_N) base[i0 + r] = run;
    run += v[r];
  }
}

__global__ void scan2_k(int* __restrict__ bsum) {
  __shared__ int ls[256];
  int tid = threadIdx.x;
  int v = (tid < SCAN_BLKS) ? bsum[tid] : 0;
  ls[tid] = v; __syncthreads();
#pragma unroll
  for (int off = 1; off < 256; off <<= 1) {
    int x = (tid >= off) ? ls[tid - off] : 0;
    __syncthreads(); ls[tid] += x; __syncthreads();
  }
  if (tid < SCAN_BLKS) bsum[tid] = ls[tid] - v;
}

// ep2 = {src | rel<<15, weight bits}; t is implicit in the segment.
// scan3 folded in: absolute position = base[key] + bsum[key>>10] + cursor++.
__global__ void fill_k(const int* __restrict__ src, const int* __restrict__ dst,
                       const int* __restrict__ etype, const int* __restrict__ etime,
                       const float* __restrict__ ew,
                       const int* __restrict__ base, const int* __restrict__ bsum,
                       int* __restrict__ cursor, uint2* __restrict__ ep2) {
  int i = blockIdx.x * blockDim.x + threadIdx.x;
  if (i >= N_EDGES) return;
  int key = dst[i] * T_STEPS + etime[i];
  int pos = base[key] + bsum[key >> 10] + atomicAdd(&cursor[key], 1);
  uint2 e;
  e.x = (unsigned)src[i] | ((unsigned)etype[i] << 15);
  e.y = __float_as_uint(ew[i]);
  ep2[pos] = e;
}

// ---------------------------------------------------------------------------
// Fully-fused GATHER + encoder + GRU recurrence. One block per 16-node tile,
// 8 waves. (R6 structure = best measured; phases A and C tightened.)
// Phase A (gather): wave wv owns nodes {2wv, 2wv+1}. NEW: the two nodes'
//   per-t segment walks are INTERLEAVED -> 2 independent load/FMA chains
//   per loop iteration (wave-uniform guards), iterations = max(len0,len1)
//   instead of len0+len1. Packed-bf16 rows -> aggL (u32/lane, conflict-free).
// ONE barrier, then:
// Phase B (encoder, hoisted): wave nt owns column tile nt; A-frags for all
//   8 t read from aggL (stride 136 shorts: 2-way bank alias = free);
//   32 MFMAs with wenc -> hpk[t] packed bf16 (16 VGPRs).
// Phase C (recurrence): per step t: H[t],S -> double-buffered LDS (stride
//   136), ONE barrier, re-read as A-frags. NEW: (a) t=0 skips the entire
//   S path (S==0; MFMA with A=0 adds exactly 0 -> bit-exact), saving
//   8 MFMAs + 4 ds_writes + 4 ds_reads; (b) gates split into 4 independent
//   4-long MFMA chains (zh,zs,ch,cs; h-chains carry bias, s-chains start at
//   0, combined by one fp32 add) -> 4-way MFMA ILP inside the convoy.
// MFMA 16x16x32_bf16 layouts (HW-verified): A: m=lane&15,k=quad*8+j;
// B: n=lane&15,k=quad*8+j;  C/D: col=lane&15, row=quad*4+reg.
// Double-buffer WAR safety: per-wave order is W(t) B(t) R(t) W(t+1) B(t+1)...
// A wave reaching W(t+2) (overwrite of buffer t&1) has passed B(t+1); every
// wave at B(t+1) completed R(t) -> no WAR hazard. Sb[0] is never written at
// t=0 and never read at t=0 -> no uninitialized reads.
// ---------------------------------------------------------------------------
__launch_bounds__(512, 4)
__global__ void fused_recur(const int* __restrict__ base,
                            const int* __restrict__ bsum,
                            const uint2* __restrict__ ep2,
                            const float* __restrict__ nemb,
                            const float* __restrict__ remb,
                            const unsigned short* __restrict__ pack,
                            const float* __restrict__ bz,
                            const float* __restrict__ bh,
                            float* __restrict__ out) {
  __shared__ unsigned short aggL[T_STEPS * 16 * 136];   // 34816 B
  __shared__ unsigned short Hb[2][16 * 136];            //  8704 B
  __shared__ unsigned short Sb[2][16 * 136];            //  8704 B
  int lane = threadIdx.x & 63;
  int nt = threadIdx.x >> 6;        // wave id: owns nodes {2nt,2nt+1} / col tile nt
  int q = lane >> 4, l15 = lane & 15;
  int tile = blockIdx.x;
  int row0 = tile * 16;
  int c = nt * 16 + l15;

  // ---- Phase A: gather this wave's 2 nodes, segments interleaved ----
  {
    int kb = (row0 + nt * 2) * T_STEPS;
    int b0[9], b1[9];
#pragma unroll
    for (int k = 0; k < 9; k++) {
      int k0 = kb + k, k1 = kb + T_STEPS + k;
      b0[k] = base[k0] + bsum[k0 >> 10];
      b1[k] = base[k1] + bsum[k1 >> 10];
    }
    int i0 = b0[0], i1 = b1[0];
#pragma unroll
    for (int tt = 0; tt < T_STEPS; tt++) {
      int e0 = b0[tt + 1], e1 = b1[tt + 1];
      float ax0 = 0.f, ay0 = 0.f, ax1 = 0.f, ay1 = 0.f;
      while (i0 < e0 || i1 < e1) {            // wave-uniform control
        if (i0 < e0) {
          uint2 e = ep2[i0++];
          float w = __uint_as_float(e.y);
          int s = e.x & 0x7fff, rt = e.x >> 15;
          float2 sv = ((const float2*)(nemb + (size_t)s * DIM))[lane];
          float2 rv = ((const float2*)(remb + (size_t)rt * DIM))[lane];
          ax0 += sv.x * rv.x * w;
          ay0 += sv.y * rv.y * w;
        }
        if (i1 < e1) {
          uint2 e = ep2[i1++];
          float w = __uint_as_float(e.y);
          int s = e.x & 0x7fff, rt = e.x >> 15;
          float2 sv = ((const float2*)(nemb + (size_t)s * DIM))[lane];
          float2 rv = ((const float2*)(remb + (size_t)rt * DIM))[lane];
          ax1 += sv.x * rv.x * w;
          ay1 += sv.y * rv.y * w;
        }
      }
      ((unsigned*)&aggL[(tt * 16 + nt * 2 + 0) * 136])[lane] = cvt_pk_bf16(ax0, ay0);
      ((unsigned*)&aggL[(tt * 16 + nt * 2 + 1) * 136])[lane] = cvt_pk_bf16(ax1, ay1);
    }
  }
  __syncthreads();

  // ---- Phase B: encoder for ALL steps: H[t](:, nt-cols) as packed bf16 ----
  unsigned hpk[T_STEPS][2];
  {
    short8 wenc[4];
#pragma unroll
    for (int ks = 0; ks < 4; ks++)
      wenc[ks] = *(const short8*)(pack + ((nt * 4 + ks) * 64 + lane) * 8);
#pragma unroll
    for (int t = 0; t < T_STEPS; t++) {
      f32x4 acch = (f32x4){0.f, 0.f, 0.f, 0.f};
#pragma unroll
      for (int ks = 0; ks < 4; ks++) {
        short8 aA = *(const short8*)&aggL[(t * 16 + l15) * 136 + ks * 32 + q * 8];
        acch = __builtin_amdgcn_mfma_f32_16x16x32_bf16(aA, wenc[ks], acch, 0, 0, 0);
      }
      hpk[t][0] = cvt_pk_bf16(fast_tanh(acch[0]), fast_tanh(acch[1]));
      hpk[t][1] = cvt_pk_bf16(fast_tanh(acch[2]), fast_tanh(acch[3]));
    }
  }

  // recurrence weight B-fragments for this wave's nt
  short8 wz[4], uz[4], wh[4], uh[4];
#pragma unroll
  for (int ks = 0; ks < 4; ks++) {
    int fo = ((nt * 4 + ks) * 64 + lane) * 8;
    wz[ks] = *(const short8*)(pack + 16384 * 1 + fo);
    uz[ks] = *(const short8*)(pack + 16384 * 2 + fo);
    wh[ks] = *(const short8*)(pack + 16384 * 3 + fo);
    uh[ks] = *(const short8*)(pack + 16384 * 4 + fo);
  }
  float bzv = bz[c];
  float bhv = bh[c];

  f32x4 stC = (f32x4){0.f, 0.f, 0.f, 0.f};

  // ---- Phase C: GRU recurrence (4-chain ILP, t=0 S-path skipped) ----
#pragma unroll
  for (int t = 0; t < T_STEPS; t++) {
    unsigned short* hB = Hb[t & 1];
    unsigned short* sB = Sb[t & 1];
    hB[(q * 4 + 0) * 136 + c] = (unsigned short)hpk[t][0];
    hB[(q * 4 + 1) * 136 + c] = (unsigned short)(hpk[t][0] >> 16);
    hB[(q * 4 + 2) * 136 + c] = (unsigned short)hpk[t][1];
    hB[(q * 4 + 3) * 136 + c] = (unsigned short)(hpk[t][1] >> 16);
    if (t > 0) {
      unsigned s01 = cvt_pk_bf16(stC[0], stC[1]);
      unsigned s23 = cvt_pk_bf16(stC[2], stC[3]);
      sB[(q * 4 + 0) * 136 + c] = (unsigned short)s01;
      sB[(q * 4 + 1) * 136 + c] = (unsigned short)(s01 >> 16);
      sB[(q * 4 + 2) * 136 + c] = (unsigned short)s23;
      sB[(q * 4 + 3) * 136 + c] = (unsigned short)(s23 >> 16);
    }
    __syncthreads();

    short8 hA[4], sA[4];
#pragma unroll
    for (int ks = 0; ks < 4; ks++)
      hA[ks] = *(const short8*)&hB[l15 * 136 + ks * 32 + q * 8];
    if (t > 0) {
#pragma unroll
      for (int ks = 0; ks < 4; ks++)
        sA[ks] = *(const short8*)&sB[l15 * 136 + ks * 32 + q * 8];
    }

    f32x4 zh = (f32x4){bzv, bzv, bzv, bzv};
    f32x4 ch = (f32x4){bhv, bhv, bhv, bhv};
    f32x4 zs = (f32x4){0.f, 0.f, 0.f, 0.f};
    f32x4 cs = (f32x4){0.f, 0.f, 0.f, 0.f};
#pragma unroll
    for (int ks = 0; ks < 4; ks++) {
      zh = __builtin_amdgcn_mfma_f32_16x16x32_bf16(hA[ks], wz[ks], zh, 0, 0, 0);
      ch = __builtin_amdgcn_mfma_f32_16x16x32_bf16(hA[ks], wh[ks], ch, 0, 0, 0);
    }
    if (t > 0) {
#pragma unroll
      for (int ks = 0; ks < 4; ks++) {
        zs = __builtin_amdgcn_mfma_f32_16x16x32_bf16(sA[ks], uz[ks], zs, 0, 0, 0);
        cs = __builtin_amdgcn_mfma_f32_16x16x32_bf16(sA[ks], uh[ks], cs, 0, 0, 0);
      }
    }
#pragma unroll
    for (int r = 0; r < 4; r++) {
      float z = fast_sig(zh[r] + zs[r]);
      float cc = fast_tanh(ch[r] + cs[r]);
      stC[r] = (1.f - z) * stC[r] + z * cc;
    }
  }

  // final state -> out (fp32, C-layout positions)
#pragma unroll
  for (int r = 0; r < 4; r++)
    out[(size_t)(row0 + q * 4 + r) * DIM + c] = stC[r];
}

extern "C" void kernel_launch(void* const* d_in, const int* in_sizes, int n_in,
                              void* d_out, int out_size, void* d_ws, size_t ws_size,
                              hipStream_t stream) {
  const int* eidx  = (const int*)d_in[0];
  const int* src   = eidx;
  const int* dst   = eidx + N_EDGES;
  const int* etype = (const int*)d_in[1];
  const int* etime = (const int*)d_in[2];
  const float* ew   = (const float*)d_in[3];
  const float* nemb = (const float*)d_in[4];
  const float* remb = (const float*)d_in[5];
  const float* Wenc = (const float*)d_in[6];
  const float* Wz   = (const float*)d_in[7];
  const float* Uz   = (const float*)d_in[8];
  const float* Wh   = (const float*)d_in[9];
  const float* Uh   = (const float*)d_in[10];
  const float* bz   = (const float*)d_in[11];
  const float* bh   = (const float*)d_in[12];
  // d_in[13] = num_times (constant 8 for this problem's fixed shapes)

  // ws layout
  int* counts = (int*)d_ws;                                        // SCAN_N
  int* cursor = counts + SCAN_N;                                   // KEYS
  int* bsum   = cursor + KEYS;                                     // 256
  int* base   = bsum + 256;                                        // SCAN_N
  uint2* ep2  = (uint2*)(base + ((SCAN_N + 1) & ~1));              // E, 8B-aligned
  unsigned short* pack = (unsigned short*)(ep2 + N_EDGES);         // 5*16384
  float* outp = (float*)d_out;

  hipMemsetAsync(counts, 0, (size_t)(SCAN_N + KEYS) * sizeof(int), stream);
  repack5<<<(5 * 16384 + 255) / 256, 256, 0, stream>>>(Wenc, Wz, Uz, Wh, Uh, pack);
  hist_k<<<(N_EDGES + 255) / 256, 256, 0, stream>>>(dst, etime, counts);
  scan1_k<<<SCAN_BLKS, 256, 0, stream>>>(counts, base, bsum);
  scan2_k<<<1, 256, 0, stream>>>(bsum);
  fill_k<<<(N_EDGES + 255) / 256, 256, 0, stream>>>(src, dst, etype, etime, ew,
                                                    base, bsum, cursor, ep2);
  fused_recur<<<N_TILES, 512, 0, stream>>>(base, bsum, ep2, nemb, remb,
                                           pack, bz, bh, outp);
}